// Round 1
// baseline (15800.494 us; speedup 1.0000x reference)
//
#include <hip/hip_runtime.h>
#include <hip/hip_bf16.h>

#define Bz 32
#define Tz 64
#define Sz 128
#define Hz 512
#define Vz 32000
#define Lz 2
#define G4 (4*Hz)

using bf16x8 = __attribute__((ext_vector_type(8))) short;
using f32x4  = __attribute__((ext_vector_type(4))) float;

__device__ __forceinline__ unsigned short f2bf(float f){
  unsigned int u = __float_as_uint(f);
  u += 0x7fffu + ((u >> 16) & 1u);
  return (unsigned short)(u >> 16);
}
__device__ __forceinline__ float sigf(float x){ return 1.f/(1.f + expf(-x)); }

// ---------------- init: h,c state ----------------
__global__ __launch_bounds__(256) void init_state_kernel(const float* __restrict__ h0,
    const float* __restrict__ c0, float* __restrict__ hbuf, float* __restrict__ cbuf){
  int i = blockIdx.x*256 + threadIdx.x;   // grid 128 -> 32768 = L*B*H
  hbuf[i] = h0[i];
  cbuf[i] = c0[i];
}

// ---------------- Wo -> bf16 ----------------
__global__ __launch_bounds__(256) void conv_bf16_kernel(const float* __restrict__ src,
    unsigned short* __restrict__ dst){
  int i = (blockIdx.x*256 + threadIdx.x)*4;  // grid 16000 -> 16,384,000
  float4 v = *(const float4*)(src + i);
  ushort4 o;
  o.x = f2bf(v.x); o.y = f2bf(v.y); o.z = f2bf(v.z); o.w = f2bf(v.w);
  *(ushort4*)(dst + i) = o;
}

// ---------------- x-path gates for layer0, all timesteps ----------------
// x0g[t][b][j] = b_ih0[j] + b_hh0[j] + emb[tgt[b,t]] . W_ih0[j]
__global__ __launch_bounds__(256) void x0g_kernel(const int* __restrict__ tgt,
    const float* __restrict__ emb, const float* __restrict__ Wih0,
    const float* __restrict__ bih0, const float* __restrict__ bhh0,
    float* __restrict__ x0g){
  int bid = blockIdx.x;          // T*B*8 = 16384
  int tb  = bid >> 3;            // t*B + b
  int j0  = (bid & 7) * 256;
  int t = tb >> 5, b = tb & 31;
  int j = j0 + threadIdx.x;
  int token = tgt[b*Tz + t];
  const float4* e4 = (const float4*)(emb + (size_t)token*Hz);
  const float4* w4 = (const float4*)(Wih0 + (size_t)j*Hz);
  float acc = bih0[j] + bhh0[j];
  #pragma unroll 4
  for (int k = 0; k < Hz/4; k++){
    float4 e = e4[k], w = w4[k];
    acc += e.x*w.x + e.y*w.y + e.z*w.z + e.w*w.w;
  }
  x0g[(size_t)tb*G4 + j] = acc;
}

// ---------------- LSTM layer 0 (recurrent part + cell) ----------------
__global__ __launch_bounds__(128) void lstm_l0_kernel(const float* __restrict__ x0g,
    float* __restrict__ hbuf, float* __restrict__ cbuf,
    const float* __restrict__ Whh0, int t, int p){
  __shared__ float h_s[Hz];
  int b = blockIdx.x >> 2, u0 = (blockIdx.x & 3)*128, tid = threadIdx.x;
  const float* hp = hbuf + ((p*Lz + 0)*Bz + b)*Hz;
  for (int i = tid; i < Hz; i += 128) h_s[i] = hp[i];
  __syncthreads();
  int u = u0 + tid;
  const float* xg = x0g + (size_t)(t*Bz + b)*G4;
  float ai = xg[u], af = xg[u+Hz], ag = xg[u+2*Hz], ao = xg[u+3*Hz];
  const float4* wi4 = (const float4*)(Whh0 + (size_t)u*Hz);
  const float4* wf4 = (const float4*)(Whh0 + (size_t)(u+Hz)*Hz);
  const float4* wg4 = (const float4*)(Whh0 + (size_t)(u+2*Hz)*Hz);
  const float4* wo4 = (const float4*)(Whh0 + (size_t)(u+3*Hz)*Hz);
  const float4* hv  = (const float4*)h_s;
  #pragma unroll 4
  for (int k = 0; k < Hz/4; k++){
    float4 h4 = hv[k], w;
    w = wi4[k]; ai += h4.x*w.x + h4.y*w.y + h4.z*w.z + h4.w*w.w;
    w = wf4[k]; af += h4.x*w.x + h4.y*w.y + h4.z*w.z + h4.w*w.w;
    w = wg4[k]; ag += h4.x*w.x + h4.y*w.y + h4.z*w.z + h4.w*w.w;
    w = wo4[k]; ao += h4.x*w.x + h4.y*w.y + h4.z*w.z + h4.w*w.w;
  }
  float ig = sigf(ai), fg = sigf(af), gg = tanhf(ag), og = sigf(ao);
  float* cp = cbuf + (0*Bz + b)*Hz + u;
  float cn = fg*(*cp) + ig*gg;
  *cp = cn;
  hbuf[(((1-p)*Lz + 0)*Bz + b)*Hz + u] = og * tanhf(cn);
}

// ---------------- LSTM layer 1 (x = new h0, recurrent + cell) ----------------
__global__ __launch_bounds__(128) void lstm_l1_kernel(
    float* __restrict__ hbuf, float* __restrict__ cbuf,
    const float* __restrict__ Wi, const float* __restrict__ Wh,
    const float* __restrict__ bi, const float* __restrict__ bh, int p){
  __shared__ float x_s[Hz], h_s[Hz];
  int b = blockIdx.x >> 2, u0 = (blockIdx.x & 3)*128, tid = threadIdx.x;
  const float* xn = hbuf + (((1-p)*Lz + 0)*Bz + b)*Hz;
  const float* hp = hbuf + ((p*Lz + 1)*Bz + b)*Hz;
  for (int i = tid; i < Hz; i += 128){ x_s[i] = xn[i]; h_s[i] = hp[i]; }
  __syncthreads();
  int u = u0 + tid;
  float ai = bi[u]      + bh[u];
  float af = bi[u+Hz]   + bh[u+Hz];
  float ag = bi[u+2*Hz] + bh[u+2*Hz];
  float ao = bi[u+3*Hz] + bh[u+3*Hz];
  const float4* xi4 = (const float4*)(Wi + (size_t)u*Hz);
  const float4* xf4 = (const float4*)(Wi + (size_t)(u+Hz)*Hz);
  const float4* xg4 = (const float4*)(Wi + (size_t)(u+2*Hz)*Hz);
  const float4* xo4 = (const float4*)(Wi + (size_t)(u+3*Hz)*Hz);
  const float4* hi4 = (const float4*)(Wh + (size_t)u*Hz);
  const float4* hf4 = (const float4*)(Wh + (size_t)(u+Hz)*Hz);
  const float4* hg4 = (const float4*)(Wh + (size_t)(u+2*Hz)*Hz);
  const float4* ho4 = (const float4*)(Wh + (size_t)(u+3*Hz)*Hz);
  const float4* xv = (const float4*)x_s;
  const float4* hv = (const float4*)h_s;
  #pragma unroll 2
  for (int k = 0; k < Hz/4; k++){
    float4 x4 = xv[k], h4 = hv[k], w;
    w = xi4[k]; ai += x4.x*w.x + x4.y*w.y + x4.z*w.z + x4.w*w.w;
    w = xf4[k]; af += x4.x*w.x + x4.y*w.y + x4.z*w.z + x4.w*w.w;
    w = xg4[k]; ag += x4.x*w.x + x4.y*w.y + x4.z*w.z + x4.w*w.w;
    w = xo4[k]; ao += x4.x*w.x + x4.y*w.y + x4.z*w.z + x4.w*w.w;
    w = hi4[k]; ai += h4.x*w.x + h4.y*w.y + h4.z*w.z + h4.w*w.w;
    w = hf4[k]; af += h4.x*w.x + h4.y*w.y + h4.z*w.z + h4.w*w.w;
    w = hg4[k]; ag += h4.x*w.x + h4.y*w.y + h4.z*w.z + h4.w*w.w;
    w = ho4[k]; ao += h4.x*w.x + h4.y*w.y + h4.z*w.z + h4.w*w.w;
  }
  float ig = sigf(ai), fg = sigf(af), gg = tanhf(ag), og = sigf(ao);
  float* cp = cbuf + (1*Bz + b)*Hz + u;
  float cn = fg*(*cp) + ig*gg;
  *cp = cn;
  hbuf[(((1-p)*Lz + 1)*Bz + b)*Hz + u] = og*tanhf(cn);
}

// ---------------- attention + out_att (one block per batch row) ----------------
__global__ __launch_bounds__(256) void attn_kernel(const float* __restrict__ hbuf,
    const float* __restrict__ enc, const float* __restrict__ Wc,
    const float* __restrict__ bc, unsigned short* __restrict__ oa, int t, int p){
  __shared__ float h_s[Hz], e_s[Sz], ctx_s[Hz];
  int b = blockIdx.x, tid = threadIdx.x;
  const float* h1 = hbuf + (((1-p)*Lz + 1)*Bz + b)*Hz;
  for (int i = tid; i < Hz; i += 256) h_s[i] = h1[i];
  __syncthreads();
  if (tid < Sz){
    const float4* e4 = (const float4*)(enc + ((size_t)b*Sz + tid)*Hz);
    const float4* h4 = (const float4*)h_s;
    float acc = 0.f;
    #pragma unroll 4
    for (int k = 0; k < Hz/4; k++){
      float4 e = e4[k], h = h4[k];
      acc += e.x*h.x + e.y*h.y + e.z*h.z + e.w*h.w;
    }
    e_s[tid] = acc;
  }
  __syncthreads();
  float m = -1e30f;
  for (int s = 0; s < Sz; s++) m = fmaxf(m, e_s[s]);
  __syncthreads();
  if (tid < Sz) e_s[tid] = expf(e_s[tid] - m);
  __syncthreads();
  float sum = 0.f;
  for (int s = 0; s < Sz; s++) sum += e_s[s];
  float inv = 1.f/sum;
  for (int k = tid; k < Hz; k += 256){
    float acc = 0.f;
    for (int s = 0; s < Sz; s++) acc += e_s[s]*enc[((size_t)b*Sz + s)*Hz + k];
    ctx_s[k] = acc*inv;
  }
  __syncthreads();
  for (int u = tid; u < Hz; u += 256){
    const float4* w1 = (const float4*)(Wc + (size_t)u*(2*Hz));
    const float4* w2 = (const float4*)(Wc + (size_t)u*(2*Hz) + Hz);
    const float4* h4 = (const float4*)h_s;
    const float4* c4 = (const float4*)ctx_s;
    float acc = bc[u];
    #pragma unroll 4
    for (int k = 0; k < Hz/4; k++){
      float4 w = w1[k], h = h4[k];
      acc += w.x*h.x + w.y*h.y + w.z*h.z + w.w*h.w;
    }
    #pragma unroll 4
    for (int k = 0; k < Hz/4; k++){
      float4 w = w2[k], c = c4[k];
      acc += w.x*c.x + w.y*c.y + w.z*c.z + w.w*c.w;
    }
    oa[((size_t)t*Bz + b)*Hz + u] = f2bf(tanhf(acc));
  }
}

// ---------------- pred GEMM: [2048 x 32000] = oa[2048x512] @ Wo^T, bf16 MFMA ----------------
__global__ __launch_bounds__(256) void pred_gemm_kernel(const unsigned short* __restrict__ A,
    const unsigned short* __restrict__ Bm, const float* __restrict__ bo,
    float* __restrict__ out){
  __shared__ unsigned short As[128*32];
  __shared__ unsigned short Bs[128*32];
  const int Kc = Hz;
  int tid = threadIdx.x;
  int lane = tid & 63, wid = tid >> 6;
  int n0 = blockIdx.x * 128;   // 250 tiles over V
  int m0 = blockIdx.y * 128;   // 16 tiles over T*B
  f32x4 acc[4][4];
  #pragma unroll
  for (int i = 0; i < 4; i++)
    #pragma unroll
    for (int j = 0; j < 4; j++)
      #pragma unroll
      for (int r = 0; r < 4; r++) acc[i][j][r] = 0.f;

  int wm = wid >> 1, wn = wid & 1;
  int r16 = lane & 15, kg8 = (lane >> 4) * 8;

  for (int kt = 0; kt < Kc/32; kt++){
    __syncthreads();
    #pragma unroll
    for (int call = 0; call < 2; call++){
      int c = call*256 + tid;        // 16B chunk id, 512 per tile
      int row = c >> 2, kg = c & 3;
      *(int4*)&As[c*8] = *(const int4*)(A  + (size_t)(m0+row)*Kc + kt*32 + kg*8);
      *(int4*)&Bs[c*8] = *(const int4*)(Bm + (size_t)(n0+row)*Kc + kt*32 + kg*8);
    }
    __syncthreads();
    bf16x8 aF[4], bF[4];
    #pragma unroll
    for (int i = 0; i < 4; i++){
      aF[i] = *(const bf16x8*)&As[(wm*64 + i*16 + r16)*32 + kg8];
      bF[i] = *(const bf16x8*)&Bs[(wn*64 + i*16 + r16)*32 + kg8];
    }
    #pragma unroll
    for (int i = 0; i < 4; i++)
      #pragma unroll
      for (int j = 0; j < 4; j++)
        acc[i][j] = __builtin_amdgcn_mfma_f32_16x16x32_bf16(aF[i], bF[j], acc[i][j], 0, 0, 0);
  }

  int rg = lane >> 4;
  #pragma unroll
  for (int i = 0; i < 4; i++)
    #pragma unroll
    for (int j = 0; j < 4; j++){
      int col = n0 + wn*64 + j*16 + r16;
      float bias = bo[col];
      #pragma unroll
      for (int r = 0; r < 4; r++){
        int row = m0 + wm*64 + i*16 + rg*4 + r;
        int tt = row >> 5, bb = row & 31;           // row = t*32 + b
        out[((size_t)bb*Tz + tt)*Vz + col] = acc[i][j][r] + bias;
      }
    }
}

// ---------------- final h,c copy ----------------
__global__ __launch_bounds__(256) void copy_hc_kernel(const float* __restrict__ hfin,
    const float* __restrict__ cbuf, float* __restrict__ out_hc){
  int i = blockIdx.x*256 + threadIdx.x;   // grid 256 -> 65536
  if (i < Lz*Bz*Hz) out_hc[i] = hfin[i];
  else              out_hc[i] = cbuf[i - Lz*Bz*Hz];
}

extern "C" void kernel_launch(void* const* d_in, const int* in_sizes, int n_in,
                              void* d_out, int out_size, void* d_ws, size_t ws_size,
                              hipStream_t stream){
  const int*   tgt = (const int*)  d_in[0];
  const float* h0  = (const float*)d_in[1];
  const float* c0  = (const float*)d_in[2];
  const float* enc = (const float*)d_in[3];
  const float* emb = (const float*)d_in[4];
  const float* Wih = (const float*)d_in[5];
  const float* Whh = (const float*)d_in[6];
  const float* bih = (const float*)d_in[7];
  const float* bhh = (const float*)d_in[8];
  const float* Wc  = (const float*)d_in[9];
  const float* bc  = (const float*)d_in[10];
  const float* Wo  = (const float*)d_in[11];
  const float* bo  = (const float*)d_in[12];
  float* out = (float*)d_out;

  // workspace layout (floats / ushorts), ~50 MB total
  float* x0g  = (float*)d_ws;                     // 4,194,304 f  (T*B*4H)
  float* hbuf = x0g + 4194304;                    // 65,536 f     ([2][L][B][H])
  float* cbuf = hbuf + 65536;                     // 32,768 f     ([L][B][H])
  unsigned short* oa    = (unsigned short*)(cbuf + 32768);  // 1,048,576 us (T*B*H)
  unsigned short* wo_bf = oa + 1048576;           // 16,384,000 us (V*H)

  init_state_kernel<<<128, 256, 0, stream>>>(h0, c0, hbuf, cbuf);
  conv_bf16_kernel<<<16000, 256, 0, stream>>>(Wo, wo_bf);
  x0g_kernel<<<16384, 256, 0, stream>>>(tgt, emb, Wih, bih, bhh, x0g);

  for (int t = 0; t < Tz; t++){
    int p = t & 1;
    lstm_l0_kernel<<<128, 128, 0, stream>>>(x0g, hbuf, cbuf, Whh, t, p);
    lstm_l1_kernel<<<128, 128, 0, stream>>>(hbuf, cbuf,
        Wih + (size_t)4*Hz*Hz, Whh + (size_t)4*Hz*Hz, bih + 4*Hz, bhh + 4*Hz, p);
    attn_kernel<<<32, 256, 0, stream>>>(hbuf, enc, Wc, bc, oa, t, p);
  }

  pred_gemm_kernel<<<dim3(250, 16), 256, 0, stream>>>(oa, wo_bf, bo, out);
  // after t=63 (p=1) the final h lives in buffer (1-p)=0 -> hbuf base
  copy_hc_kernel<<<256, 256, 0, stream>>>(hbuf, cbuf, out + (size_t)Bz*Tz*Vz);

  (void)in_sizes; (void)n_in; (void)out_size; (void)ws_size;
}

// Round 2
// 5905.871 us; speedup vs baseline: 2.6754x; 2.6754x over previous
//
#include <hip/hip_runtime.h>
#include <hip/hip_bf16.h>

#define Bz 32
#define Tz 64
#define Sz 128
#define Hz 512
#define Vz 32000
#define Lz 2
#define G4 (4*Hz)

using bf16x8 = __attribute__((ext_vector_type(8))) short;
using f32x4  = __attribute__((ext_vector_type(4))) float;

__device__ __forceinline__ unsigned short f2bf(float f){
  unsigned int u = __float_as_uint(f);
  u += 0x7fffu + ((u >> 16) & 1u);
  return (unsigned short)(u >> 16);
}
__device__ __forceinline__ float sigf(float x){ return 1.f/(1.f + expf(-x)); }

// ---------------- init: h,c state ----------------
__global__ __launch_bounds__(256) void init_state_kernel(const float* __restrict__ h0,
    const float* __restrict__ c0, float* __restrict__ hbuf, float* __restrict__ cbuf){
  int i = blockIdx.x*256 + threadIdx.x;   // grid 128 -> 32768 = L*B*H
  hbuf[i] = h0[i];
  cbuf[i] = c0[i];
}

// ---------------- Wo -> bf16 ----------------
__global__ __launch_bounds__(256) void conv_bf16_kernel(const float* __restrict__ src,
    unsigned short* __restrict__ dst){
  int i = (blockIdx.x*256 + threadIdx.x)*4;  // grid 16000 -> 16,384,000
  float4 v = *(const float4*)(src + i);
  ushort4 o;
  o.x = f2bf(v.x); o.y = f2bf(v.y); o.z = f2bf(v.z); o.w = f2bf(v.w);
  *(ushort4*)(dst + i) = o;
}

// ---------------- weight packing: WTp[kb][r] (float4), r = u*4+gate ----------------
__global__ __launch_bounds__(256) void pack_l0_kernel(const float* __restrict__ W,
    float* __restrict__ out){
  int idx = blockIdx.x*256 + threadIdx.x;   // 128*2048 -> 1024 blocks
  int r = idx & 2047, kb = idx >> 11;
  int row = (r & 3)*Hz + (r >> 2);
  *(float4*)(out + (size_t)idx*4) = *(const float4*)(W + (size_t)row*Hz + kb*4);
}
__global__ __launch_bounds__(256) void pack_l1_kernel(const float* __restrict__ Wi,
    const float* __restrict__ Wh, float* __restrict__ out){
  int idx = blockIdx.x*256 + threadIdx.x;   // 256*2048 -> 2048 blocks
  int r = idx & 2047, kb = idx >> 11;
  int row = (r & 3)*Hz + (r >> 2);
  const float* src = (kb < 128) ? (Wi + (size_t)row*Hz + kb*4)
                                : (Wh + (size_t)row*Hz + (kb-128)*4);
  *(float4*)(out + (size_t)idx*4) = *(const float4*)src;
}
__global__ __launch_bounds__(256) void pack_wc_kernel(const float* __restrict__ Wc,
    float* __restrict__ out){
  int idx = blockIdx.x*256 + threadIdx.x;   // 256*512 -> 512 blocks
  int u = idx & 511, kb = idx >> 9;
  *(float4*)(out + (size_t)idx*4) = *(const float4*)(Wc + (size_t)u*(2*Hz) + kb*4);
}

// ---------------- x0g: tiled fp32 GEMM  x0g[tb][j] = emb[tok(tb)] . Wih0[j] + biases ----
__global__ __launch_bounds__(256) void x0g_v2(const int* __restrict__ tgt,
    const float* __restrict__ emb, const float* __restrict__ W,
    const float* __restrict__ bi, const float* __restrict__ bh,
    float* __restrict__ out){
  __shared__ float As[32][68], Bs[32][68];
  __shared__ int tok_s[64];
  int tid = threadIdx.x;
  int m0 = blockIdx.y*64, n0 = blockIdx.x*64;
  if (tid < 64){ int tb = m0 + tid; tok_s[tid] = tgt[(tb & 31)*Tz + (tb >> 5)]; }
  __syncthreads();
  int lm = tid >> 2, lk = (tid & 3)*8;
  int ty = tid >> 4, tx = tid & 15;
  float acc[4][4] = {{0.f}};
  for (int kt = 0; kt < 16; kt++){
    float4 a0 = *(const float4*)(emb + (size_t)tok_s[lm]*Hz + kt*32 + lk);
    float4 a1 = *(const float4*)(emb + (size_t)tok_s[lm]*Hz + kt*32 + lk + 4);
    float4 b0 = *(const float4*)(W   + (size_t)(n0+lm)*Hz + kt*32 + lk);
    float4 b1 = *(const float4*)(W   + (size_t)(n0+lm)*Hz + kt*32 + lk + 4);
    __syncthreads();   // protect previous-iter LDS reads
    As[lk+0][lm]=a0.x; As[lk+1][lm]=a0.y; As[lk+2][lm]=a0.z; As[lk+3][lm]=a0.w;
    As[lk+4][lm]=a1.x; As[lk+5][lm]=a1.y; As[lk+6][lm]=a1.z; As[lk+7][lm]=a1.w;
    Bs[lk+0][lm]=b0.x; Bs[lk+1][lm]=b0.y; Bs[lk+2][lm]=b0.z; Bs[lk+3][lm]=b0.w;
    Bs[lk+4][lm]=b1.x; Bs[lk+5][lm]=b1.y; Bs[lk+6][lm]=b1.z; Bs[lk+7][lm]=b1.w;
    __syncthreads();
    #pragma unroll
    for (int k = 0; k < 32; k++){
      float4 av = *(const float4*)&As[k][ty*4];
      float4 bv = *(const float4*)&Bs[k][tx*4];
      acc[0][0]+=av.x*bv.x; acc[0][1]+=av.x*bv.y; acc[0][2]+=av.x*bv.z; acc[0][3]+=av.x*bv.w;
      acc[1][0]+=av.y*bv.x; acc[1][1]+=av.y*bv.y; acc[1][2]+=av.y*bv.z; acc[1][3]+=av.y*bv.w;
      acc[2][0]+=av.z*bv.x; acc[2][1]+=av.z*bv.y; acc[2][2]+=av.z*bv.z; acc[2][3]+=av.z*bv.w;
      acc[3][0]+=av.w*bv.x; acc[3][1]+=av.w*bv.y; acc[3][2]+=av.w*bv.z; acc[3][3]+=av.w*bv.w;
    }
  }
  #pragma unroll
  for (int j = 0; j < 4; j++){
    int col = n0 + tx*4 + j;
    float bias = bi[col] + bh[col];
    #pragma unroll
    for (int i = 0; i < 4; i++)
      out[(size_t)(m0 + ty*4 + i)*G4 + col] = acc[i][j] + bias;
  }
}

// ---------------- LSTM layer0: gates = x0g + h @ Whh^T (packed) ----------------
// grid 128: blockIdx = bg*8 + g ; chunk g -> XCD g ; bgroup of 2 b's
__global__ __launch_bounds__(256) void lstm_l0_v2(const float* __restrict__ WTp,
    const float* __restrict__ x0g, float* __restrict__ hbuf, float* __restrict__ cbuf,
    int t, int p){
  const int g = blockIdx.x & 7, bg = blockIdx.x >> 3;
  const int tid = threadIdx.x;
  const int r = g*256 + tid;
  const int b0 = bg*2;
  const float* __restrict__ ha = hbuf + ((p*Lz + 0)*Bz + b0)*Hz;
  const float* __restrict__ hb = ha + Hz;
  const float* __restrict__ w  = WTp + (size_t)r*4;
  float acc0 = 0.f, acc1 = 0.f;
  #pragma unroll 8
  for (int kb = 0; kb < 128; kb++){
    float4 wv = *(const float4*)(w + (size_t)kb*8192);
    float4 xa = *(const float4*)(ha + kb*4);
    float4 xb = *(const float4*)(hb + kb*4);
    acc0 += wv.x*xa.x + wv.y*xa.y + wv.z*xa.z + wv.w*xa.w;
    acc1 += wv.x*xb.x + wv.y*xb.y + wv.z*xb.z + wv.w*xb.w;
  }
  // lanes r = u*4+gate: gates of u are adjacent lanes
  float f_0 = __shfl_down(acc0, 1), g_0 = __shfl_down(acc0, 2), o_0 = __shfl_down(acc0, 3);
  float f_1 = __shfl_down(acc1, 1), g_1 = __shfl_down(acc1, 2), o_1 = __shfl_down(acc1, 3);
  if ((tid & 3) == 0){
    int u = g*64 + (tid >> 2);
    const float* xg0 = x0g + (size_t)(t*Bz + b0)*G4;
    const float* xg1 = xg0 + G4;
    float ai = xg0[u] + acc0, af = xg0[u+Hz] + f_0, ag = xg0[u+2*Hz] + g_0, ao = xg0[u+3*Hz] + o_0;
    float* cp0 = cbuf + (0*Bz + b0)*Hz + u;
    float cn0 = sigf(af)*cp0[0] + sigf(ai)*tanhf(ag);
    cp0[0] = cn0;
    hbuf[(((1-p)*Lz + 0)*Bz + b0)*Hz + u] = sigf(ao)*tanhf(cn0);
    ai = xg1[u] + acc1; af = xg1[u+Hz] + f_1; ag = xg1[u+2*Hz] + g_1; ao = xg1[u+3*Hz] + o_1;
    float* cp1 = cbuf + (0*Bz + b0 + 1)*Hz + u;
    float cn1 = sigf(af)*cp1[0] + sigf(ai)*tanhf(ag);
    cp1[0] = cn1;
    hbuf[(((1-p)*Lz + 0)*Bz + b0 + 1)*Hz + u] = sigf(ao)*tanhf(cn1);
  }
}

// ---------------- LSTM layer1: gates = [x,h] @ [Wi,Wh]^T (packed K=1024) ----------------
__global__ __launch_bounds__(256) void lstm_l1_v2(const float* __restrict__ WTp,
    const float* __restrict__ bi, const float* __restrict__ bh,
    float* __restrict__ hbuf, float* __restrict__ cbuf, int p){
  const int g = blockIdx.x & 7, bg = blockIdx.x >> 3;
  const int tid = threadIdx.x;
  const int r = g*256 + tid;
  const int b0 = bg*2;
  const float* __restrict__ xa = hbuf + (((1-p)*Lz + 0)*Bz + b0)*Hz;  // x = new h0
  const float* __restrict__ xb = xa + Hz;
  const float* __restrict__ ha = hbuf + ((p*Lz + 1)*Bz + b0)*Hz;      // h = prev h1
  const float* __restrict__ hb = ha + Hz;
  const float* __restrict__ w  = WTp + (size_t)r*4;
  float acc0 = 0.f, acc1 = 0.f;
  #pragma unroll 8
  for (int kb = 0; kb < 128; kb++){
    float4 wv = *(const float4*)(w + (size_t)kb*8192);
    float4 va = *(const float4*)(xa + kb*4);
    float4 vb = *(const float4*)(xb + kb*4);
    acc0 += wv.x*va.x + wv.y*va.y + wv.z*va.z + wv.w*va.w;
    acc1 += wv.x*vb.x + wv.y*vb.y + wv.z*vb.z + wv.w*vb.w;
  }
  #pragma unroll 8
  for (int kb = 0; kb < 128; kb++){
    float4 wv = *(const float4*)(w + (size_t)(128 + kb)*8192);
    float4 va = *(const float4*)(ha + kb*4);
    float4 vb = *(const float4*)(hb + kb*4);
    acc0 += wv.x*va.x + wv.y*va.y + wv.z*va.z + wv.w*va.w;
    acc1 += wv.x*vb.x + wv.y*vb.y + wv.z*vb.z + wv.w*vb.w;
  }
  float f_0 = __shfl_down(acc0, 1), g_0 = __shfl_down(acc0, 2), o_0 = __shfl_down(acc0, 3);
  float f_1 = __shfl_down(acc1, 1), g_1 = __shfl_down(acc1, 2), o_1 = __shfl_down(acc1, 3);
  if ((tid & 3) == 0){
    int u = g*64 + (tid >> 2);
    float bsi = bi[u]        + bh[u];
    float bsf = bi[u+Hz]     + bh[u+Hz];
    float bsg = bi[u+2*Hz]   + bh[u+2*Hz];
    float bso = bi[u+3*Hz]   + bh[u+3*Hz];
    float ai = bsi + acc0, af = bsf + f_0, ag = bsg + g_0, ao = bso + o_0;
    float* cp0 = cbuf + (1*Bz + b0)*Hz + u;
    float cn0 = sigf(af)*cp0[0] + sigf(ai)*tanhf(ag);
    cp0[0] = cn0;
    hbuf[(((1-p)*Lz + 1)*Bz + b0)*Hz + u] = sigf(ao)*tanhf(cn0);
    ai = bsi + acc1; af = bsf + f_1; ag = bsg + g_1; ao = bso + o_1;
    float* cp1 = cbuf + (1*Bz + b0 + 1)*Hz + u;
    float cn1 = sigf(af)*cp1[0] + sigf(ai)*tanhf(ag);
    cp1[0] = cn1;
    hbuf[(((1-p)*Lz + 1)*Bz + b0 + 1)*Hz + u] = sigf(ao)*tanhf(cn1);
  }
}

// ---------------- attention + out_att ----------------
__global__ __launch_bounds__(256) void attn_v2(const float* __restrict__ hbuf,
    const float* __restrict__ enc, const float* __restrict__ WcTp,
    const float* __restrict__ bc, unsigned short* __restrict__ oa, int t, int p){
  __shared__ float h_s[Hz], ctx_s[Hz], e_s[Sz], red_s[2];
  const int b = blockIdx.x, tid = threadIdx.x;
  const float* __restrict__ h1 = hbuf + (((1-p)*Lz + 1)*Bz + b)*Hz;
  *(float2*)(h_s + tid*2) = *(const float2*)(h1 + tid*2);
  __syncthreads();
  { // scores: 2 threads per s
    int s = tid >> 1, half = tid & 1;
    const float4* e4 = (const float4*)(enc + ((size_t)b*Sz + s)*Hz + half*256);
    const float4* h4 = (const float4*)(h_s + half*256);
    float a = 0.f;
    #pragma unroll 8
    for (int k = 0; k < 64; k++){
      float4 e = e4[k], h = h4[k];
      a += e.x*h.x + e.y*h.y + e.z*h.z + e.w*h.w;
    }
    a += __shfl_xor(a, 1);
    if (!half) e_s[s] = a;
  }
  __syncthreads();
  if (tid < 64){
    float v = fmaxf(e_s[tid], e_s[tid+64]);
    #pragma unroll
    for (int off = 32; off; off >>= 1) v = fmaxf(v, __shfl_xor(v, off));
    if (tid == 0) red_s[0] = v;
  }
  __syncthreads();
  if (tid < Sz) e_s[tid] = expf(e_s[tid] - red_s[0]);
  __syncthreads();
  if (tid < 64){
    float v = e_s[tid] + e_s[tid+64];
    #pragma unroll
    for (int off = 32; off; off >>= 1) v += __shfl_xor(v, off);
    if (tid == 0) red_s[1] = v;
  }
  __syncthreads();
  { // context: 2 k per thread
    float inv = 1.f / red_s[1];
    int k0 = tid*2;
    float c0 = 0.f, c1 = 0.f;
    const float* ep = enc + (size_t)b*Sz*Hz + k0;
    #pragma unroll 4
    for (int s = 0; s < Sz; s++){
      float2 ev = *(const float2*)(ep + (size_t)s*Hz);
      float pr = e_s[s];
      c0 += pr*ev.x; c1 += pr*ev.y;
    }
    ctx_s[k0] = c0*inv; ctx_s[k0+1] = c1*inv;
  }
  __syncthreads();
  { // out_att: u = tid and tid+256
    float a0 = bc[tid], a1 = bc[tid+256];
    #pragma unroll 4
    for (int kb = 0; kb < 128; kb++){
      float4 w0 = *(const float4*)(WcTp + ((size_t)kb*512 + tid)*4);
      float4 w1 = *(const float4*)(WcTp + ((size_t)kb*512 + tid + 256)*4);
      float4 x  = *(const float4*)(h_s + kb*4);
      a0 += w0.x*x.x + w0.y*x.y + w0.z*x.z + w0.w*x.w;
      a1 += w1.x*x.x + w1.y*x.y + w1.z*x.z + w1.w*x.w;
    }
    #pragma unroll 4
    for (int kb = 0; kb < 128; kb++){
      float4 w0 = *(const float4*)(WcTp + ((size_t)(128+kb)*512 + tid)*4);
      float4 w1 = *(const float4*)(WcTp + ((size_t)(128+kb)*512 + tid + 256)*4);
      float4 x  = *(const float4*)(ctx_s + kb*4);
      a0 += w0.x*x.x + w0.y*x.y + w0.z*x.z + w0.w*x.w;
      a1 += w1.x*x.x + w1.y*x.y + w1.z*x.z + w1.w*x.w;
    }
    unsigned short* op = oa + ((size_t)t*Bz + b)*Hz;
    op[tid]     = f2bf(tanhf(a0));
    op[tid+256] = f2bf(tanhf(a1));
  }
}

// ---------------- pred GEMM: [2048 x 32000] = oa[2048x512] @ Wo^T, bf16 MFMA ----------------
__global__ __launch_bounds__(256) void pred_gemm_kernel(const unsigned short* __restrict__ A,
    const unsigned short* __restrict__ Bm, const float* __restrict__ bo,
    float* __restrict__ out){
  __shared__ unsigned short As[128*32];
  __shared__ unsigned short Bs[128*32];
  const int Kc = Hz;
  int tid = threadIdx.x;
  int lane = tid & 63, wid = tid >> 6;
  int n0 = blockIdx.x * 128;
  int m0 = blockIdx.y * 128;
  f32x4 acc[4][4];
  #pragma unroll
  for (int i = 0; i < 4; i++)
    #pragma unroll
    for (int j = 0; j < 4; j++)
      #pragma unroll
      for (int r = 0; r < 4; r++) acc[i][j][r] = 0.f;

  int wm = wid >> 1, wn = wid & 1;
  int r16 = lane & 15, kg8 = (lane >> 4) * 8;

  for (int kt = 0; kt < Kc/32; kt++){
    __syncthreads();
    #pragma unroll
    for (int call = 0; call < 2; call++){
      int c = call*256 + tid;
      int row = c >> 2, kg = c & 3;
      *(int4*)&As[c*8] = *(const int4*)(A  + (size_t)(m0+row)*Kc + kt*32 + kg*8);
      *(int4*)&Bs[c*8] = *(const int4*)(Bm + (size_t)(n0+row)*Kc + kt*32 + kg*8);
    }
    __syncthreads();
    bf16x8 aF[4], bF[4];
    #pragma unroll
    for (int i = 0; i < 4; i++){
      aF[i] = *(const bf16x8*)&As[(wm*64 + i*16 + r16)*32 + kg8];
      bF[i] = *(const bf16x8*)&Bs[(wn*64 + i*16 + r16)*32 + kg8];
    }
    #pragma unroll
    for (int i = 0; i < 4; i++)
      #pragma unroll
      for (int j = 0; j < 4; j++)
        acc[i][j] = __builtin_amdgcn_mfma_f32_16x16x32_bf16(aF[i], bF[j], acc[i][j], 0, 0, 0);
  }

  int rg = lane >> 4;
  #pragma unroll
  for (int i = 0; i < 4; i++)
    #pragma unroll
    for (int j = 0; j < 4; j++){
      int col = n0 + wn*64 + j*16 + r16;
      float bias = bo[col];
      #pragma unroll
      for (int r = 0; r < 4; r++){
        int row = m0 + wm*64 + i*16 + rg*4 + r;
        int tt = row >> 5, bb = row & 31;
        out[((size_t)bb*Tz + tt)*Vz + col] = acc[i][j][r] + bias;
      }
    }
}

// ---------------- final h,c copy ----------------
__global__ __launch_bounds__(256) void copy_hc_kernel(const float* __restrict__ hfin,
    const float* __restrict__ cbuf, float* __restrict__ out_hc){
  int i = blockIdx.x*256 + threadIdx.x;
  if (i < Lz*Bz*Hz) out_hc[i] = hfin[i];
  else              out_hc[i] = cbuf[i - Lz*Bz*Hz];
}

extern "C" void kernel_launch(void* const* d_in, const int* in_sizes, int n_in,
                              void* d_out, int out_size, void* d_ws, size_t ws_size,
                              hipStream_t stream){
  const int*   tgt = (const int*)  d_in[0];
  const float* h0  = (const float*)d_in[1];
  const float* c0  = (const float*)d_in[2];
  const float* enc = (const float*)d_in[3];
  const float* emb = (const float*)d_in[4];
  const float* Wih = (const float*)d_in[5];
  const float* Whh = (const float*)d_in[6];
  const float* bih = (const float*)d_in[7];
  const float* bhh = (const float*)d_in[8];
  const float* Wc  = (const float*)d_in[9];
  const float* bc  = (const float*)d_in[10];
  const float* Wo  = (const float*)d_in[11];
  const float* bo  = (const float*)d_in[12];
  float* out = (float*)d_out;

  // workspace layout (~64 MB)
  float* x0g  = (float*)d_ws;                     // 4,194,304 f
  float* hbuf = x0g + 4194304;                    // 65,536 f  [2 pingpong][L][B][H]
  float* cbuf = hbuf + 65536;                     // 32,768 f  [L][B][H]
  float* WTp0 = cbuf + 32768;                     // 1,048,576 f (4MB)
  float* WTp1 = WTp0 + 1048576;                   // 2,097,152 f (8MB)
  float* WcTp = WTp1 + 2097152;                   // 524,288 f (2MB)
  unsigned short* oa    = (unsigned short*)(WcTp + 524288);  // 1,048,576 us
  unsigned short* wo_bf = oa + 1048576;           // 16,384,000 us (32MB)

  init_state_kernel<<<128, 256, 0, stream>>>(h0, c0, hbuf, cbuf);
  conv_bf16_kernel<<<16000, 256, 0, stream>>>(Wo, wo_bf);
  pack_l0_kernel<<<1024, 256, 0, stream>>>(Whh, WTp0);
  pack_l1_kernel<<<2048, 256, 0, stream>>>(Wih + (size_t)G4*Hz, Whh + (size_t)G4*Hz, WTp1);
  pack_wc_kernel<<<512, 256, 0, stream>>>(Wc, WcTp);
  x0g_v2<<<dim3(32, 32), 256, 0, stream>>>(tgt, emb, Wih, bih, bhh, x0g);

  for (int t = 0; t < Tz; t++){
    int p = t & 1;
    lstm_l0_v2<<<128, 256, 0, stream>>>(WTp0, x0g, hbuf, cbuf, t, p);
    lstm_l1_v2<<<128, 256, 0, stream>>>(WTp1, bih + G4, bhh + G4, hbuf, cbuf, p);
    attn_v2<<<32, 256, 0, stream>>>(hbuf, enc, WcTp, bc, oa, t, p);
  }

  pred_gemm_kernel<<<dim3(250, 16), 256, 0, stream>>>(oa, wo_bf, bo, out);
  copy_hc_kernel<<<256, 256, 0, stream>>>(hbuf, cbuf, out + (size_t)Bz*Tz*Vz);

  (void)in_sizes; (void)n_in; (void)out_size; (void)ws_size;
}